// Round 12
// baseline (440.063 us; speedup 1.0000x reference)
//
#include <hip/hip_runtime.h>
#include <math.h>

#define LOG2PI 1.8378770664093453f
#define F32MIN (-3.4028234663852886e38f)
#define SMAX 384       // S (lane math assumes 384 = 64 lanes * 6 cols)
#define RSTRIDE 392    // padded LDS row stride (floats): rows differ by 32B mod 128B
#define NCH 75         // 16-row chunks (T == 1200)

// ---------------------------------------------------------------------------
// Kernel 1: row sums of squares  lx2[b,t] = sum_c latent^2, lm2[b,s] = sum_c mean^2
__global__ __launch_bounds__(64) void k_sums(
    const float* __restrict__ latent, const float* __restrict__ mean,
    float* __restrict__ lx2, float* __restrict__ lm2, int BT, int BS, int C) {
  int row = blockIdx.x;
  int lane = threadIdx.x;
  const float* src;
  float* dst;
  if (row < BT) { src = latent + (size_t)row * C; dst = lx2 + row; }
  else          { src = mean + (size_t)(row - BT) * C; dst = lm2 + (row - BT); }
  float s = 0.f;
  for (int c = lane; c < C; c += 64) { float v = src[c]; s += v * v; }
  #pragma unroll
  for (int off = 32; off; off >>= 1) s += __shfl_down(s, off);
  if (lane == 0) *dst = s;
}

// ---------------------------------------------------------------------------
// Kernel 2: ll[b,t,s] = -0.5*(LOG2PI + lx2 - 2*dot + lm2) * attnmask
__global__ __launch_bounds__(256) void k_scores(
    const float* __restrict__ latent, const float* __restrict__ mean,
    const float* __restrict__ lx2, const float* __restrict__ lm2,
    const int* __restrict__ textlen, const int* __restrict__ mellen,
    float* __restrict__ ll, int T, int S, int C) {
  int b  = blockIdx.z;
  int t0 = blockIdx.x * 64;
  int s0 = blockIdx.y * 64;
  int mel = mellen[b], txt = textlen[b];
  int tid = threadIdx.x;
  int ty = tid >> 4, tx = tid & 15;
  float* out = ll + ((size_t)b * T + t0) * S + s0;

  if (t0 >= mel || s0 >= txt) {
    float4 z = make_float4(0.f, 0.f, 0.f, 0.f);
    #pragma unroll
    for (int i = 0; i < 4; ++i) {
      int tl = ty * 4 + i;
      if (t0 + tl < T) *(float4*)(out + (size_t)tl * S + tx * 4) = z;
    }
    return;
  }

  __shared__ float At[16][64];
  __shared__ float Bt[16][64];
  float acc[4][4] = {};

  const float* Ab = latent + ((size_t)b * T + t0) * C;
  const float* Bb = mean + ((size_t)b * S + s0) * C;

  for (int kk = 0; kk < C; kk += 16) {
    int r  = tid >> 2;
    int cg = tid & 3;
    float4 a = (t0 + r < T) ? *(const float4*)(Ab + (size_t)r * C + kk + cg * 4)
                            : make_float4(0.f, 0.f, 0.f, 0.f);
    float4 bm = *(const float4*)(Bb + (size_t)r * C + kk + cg * 4);
    At[cg * 4 + 0][r] = a.x;  At[cg * 4 + 1][r] = a.y;
    At[cg * 4 + 2][r] = a.z;  At[cg * 4 + 3][r] = a.w;
    Bt[cg * 4 + 0][r] = bm.x; Bt[cg * 4 + 1][r] = bm.y;
    Bt[cg * 4 + 2][r] = bm.z; Bt[cg * 4 + 3][r] = bm.w;
    __syncthreads();
    #pragma unroll
    for (int k = 0; k < 16; ++k) {
      float4 a4 = *(const float4*)&At[k][ty * 4];
      float4 b4 = *(const float4*)&Bt[k][tx * 4];
      float av[4] = {a4.x, a4.y, a4.z, a4.w};
      float bv[4] = {b4.x, b4.y, b4.z, b4.w};
      #pragma unroll
      for (int i = 0; i < 4; ++i)
        #pragma unroll
        for (int j = 0; j < 4; ++j)
          acc[i][j] = fmaf(av[i], bv[j], acc[i][j]);
    }
    __syncthreads();
  }

  #pragma unroll
  for (int i = 0; i < 4; ++i) {
    int t = t0 + ty * 4 + i;
    if (t >= T) continue;
    float lx = lx2[(size_t)b * T + t];
    float4 o;
    float* po = &o.x;
    #pragma unroll
    for (int j = 0; j < 4; ++j) {
      int s = s0 + tx * 4 + j;
      float d = lx - 2.f * acc[i][j] + lm2[(size_t)b * S + s];
      float v = -0.5f * (LOG2PI + d);
      po[j] = (t < mel && s < txt) ? v : 0.f;
    }
    *(float4*)(out + (size_t)(ty * 4 + i) * S + tx * 4) = o;
  }
}

// ---------------------------------------------------------------------------
// DPP wave_shr:1 — lane l gets lane l-1's value, lane 0 gets -inf. Pure VALU.
__device__ __forceinline__ float dpp_shr1_neginf(float x) {
  int r = __builtin_amdgcn_update_dpp(
      __float_as_int(-INFINITY), __float_as_int(x),
      0x138 /*wave_shr:1*/, 0xf, 0xf, false);
  return __int_as_float(r);
}

// Per-batch scan state: 6 running probs + 6 inverted-bit accumulators.
struct MasState {
  float p0, p1, p2, p3, p4, p5;
  unsigned n0, n1, n2, n3, n4, n5;
};

// One MAS step — VCC-free (R10-verified math). Max via v_max_f32; direction
// bit via sign(p - q) (p>=q <=> signbit(p-q)==0 here; ties give +0, and -0
// never arises since ll is exactly 0 or <= -0.9). Inverted bits accumulated,
// flush writes ~n. r is wave-uniform.
template <bool MASKED>
__device__ __forceinline__ void mas_step(
    int t, int sbase, int r, const float2 A0, const float2 A1, const float2 A2,
    MasState& st) {
  float l0 = A0.x, l1 = A0.y, l2 = A1.x, l3 = A1.y, l4 = A2.x, l5 = A2.y;
  float pm1 = dpp_shr1_neginf(st.p5);
  unsigned s0b = __float_as_uint(st.p0 - pm1)   >> 31;
  unsigned s1b = __float_as_uint(st.p1 - st.p0) >> 31;
  unsigned s2b = __float_as_uint(st.p2 - st.p1) >> 31;
  unsigned s3b = __float_as_uint(st.p3 - st.p2) >> 31;
  unsigned s4b = __float_as_uint(st.p4 - st.p3) >> 31;
  unsigned s5b = __float_as_uint(st.p5 - st.p4) >> 31;
  st.n0 |= s0b << r; st.n1 |= s1b << r; st.n2 |= s2b << r;
  st.n3 |= s3b << r; st.n4 |= s4b << r; st.n5 |= s5b << r;
  float v0 = fmaxf(st.p0, pm1) + l0;
  float v1 = fmaxf(st.p1, st.p0) + l1;
  float v2 = fmaxf(st.p2, st.p1) + l2;
  float v3 = fmaxf(st.p3, st.p2) + l3;
  float v4 = fmaxf(st.p4, st.p3) + l4;
  float v5 = fmaxf(st.p5, st.p4) + l5;
  if (MASKED) {
    st.p0 = (sbase + 0 <= t) ? v0 : F32MIN;
    st.p1 = (sbase + 1 <= t) ? v1 : F32MIN;
    st.p2 = (sbase + 2 <= t) ? v2 : F32MIN;
    st.p3 = (sbase + 3 <= t) ? v3 : F32MIN;
    st.p4 = (sbase + 4 <= t) ? v4 : F32MIN;
    st.p5 = (sbase + 5 <= t) ? v5 : F32MIN;
  } else {
    st.p0 = v0; st.p1 = v1; st.p2 = v2; st.p3 = v3; st.p4 = v4; st.p5 = v5;
  }
}

// 16 steps of BOTH batches, interleaved at step granularity so the two
// independent chains cover each other's waits. 2-deep read-ahead per batch
// (R9 pattern — the low-bank-conflict depth).
template <bool MASKED>
__device__ __forceinline__ void scan_pair16(
    const float* __restrict__ r0, const float* __restrict__ r1,
    int t0, int sbase, MasState& s0, MasState& s1) {
  const float2* qA = (const float2*)(r0 + sbase);   // row stride = 196 float2
  const float2* qB = (const float2*)(r1 + sbase);
  float2 Xa0 = qA[0], Xa1 = qA[1], Xa2 = qA[2];
  float2 Ya0 = qB[0], Ya1 = qB[1], Ya2 = qB[2];
  #pragma unroll 1
  for (int u = 0; u < 16; u += 2) {
    const float2* pa = qA + (size_t)(u + 1) * (RSTRIDE / 2);
    float2 Xb0 = pa[0], Xb1 = pa[1], Xb2 = pa[2];
    const float2* pb = qB + (size_t)(u + 1) * (RSTRIDE / 2);
    float2 Yb0 = pb[0], Yb1 = pb[1], Yb2 = pb[2];
    int r = (t0 + u) & 31;
    mas_step<MASKED>(t0 + u, sbase, r, Xa0, Xa1, Xa2, s0);
    mas_step<MASKED>(t0 + u, sbase, r, Ya0, Ya1, Ya2, s1);
    int un = (u + 2 < 16) ? u + 2 : 15;   // clamp: dummy in-bounds read
    const float2* na = qA + (size_t)un * (RSTRIDE / 2);
    Xa0 = na[0]; Xa1 = na[1]; Xa2 = na[2];
    const float2* nb = qB + (size_t)un * (RSTRIDE / 2);
    Ya0 = nb[0]; Ya1 = nb[1]; Ya2 = nb[2];
    mas_step<MASKED>(t0 + u + 1, sbase, r + 1, Xb0, Xb1, Xb2, s0);
    mas_step<MASKED>(t0 + u + 1, sbase, r + 1, Yb0, Yb1, Yb2, s1);
  }
}

__device__ __forceinline__ void flush_dir(unsigned* dst, MasState& st) {
  dst[0] = ~st.n0; dst[1] = ~st.n1; dst[2] = ~st.n2;
  dst[3] = ~st.n3; dst[4] = ~st.n4; dst[5] = ~st.n5;
  st.n0 = st.n1 = st.n2 = st.n3 = st.n4 = st.n5 = 0;
}

// ---------------------------------------------------------------------------
// Kernel 3a: MAS forward. One block (3 waves) per PAIR of batches.
// Wave 0 scans both batches' chains interleaved; waves 1/2 each double-buffer
// one batch's next 16-row chunk global->reg->LDS.
// Direction words go to GLOBAL, word-major dirT[b][w][col], stored in the
// already-consumed prefix of ll[b] (flush f writes [f*1536, f*1536+1536) —
// always far below the 49KB*(f+1) dead zone; disjoint from all later reads).
// NOTE: ll is NOT __restrict__ here (dir pointers alias it by design).
// Assumes S == 384, T == 1200.
__global__ __launch_bounds__(192, 1) void k_fwd(
    float* llbase, int T, int S) {
  int pb = blockIdx.x;                  // batch pair
  int tid = threadIdx.x;
  int lane = tid & 63;
  int wv = tid >> 6;
  __shared__ float rows[2][2][17][RSTRIDE];   // [buf][batch][row(+pad)][col]

  if (wv >= 1) {
    int q = wv - 1;
    const float* gb = llbase + (size_t)(pb * 2 + q) * T * S;
    // prologue: chunk 0 (16 rows * 384 floats = 1536 float4; 24 per lane)
    {
      const float4* g = (const float4*)gb;
      float4 stg[24];
      #pragma unroll
      for (int k = 0; k < 24; ++k) stg[k] = g[k * 64 + lane];
      #pragma unroll
      for (int k = 0; k < 24; ++k) {
        int f = k * 64 + lane;
        ((float4*)&rows[0][q][f / 96][0])[f % 96] = stg[k];
      }
    }
    __syncthreads();
    for (int c = 0; c < NCH; ++c) {
      if (c + 1 < NCH) {
        const float4* g = (const float4*)(gb + (size_t)(c + 1) * 16 * S);
        float4 stg[24];
        #pragma unroll
        for (int k = 0; k < 24; ++k) stg[k] = g[k * 64 + lane];
        #pragma unroll
        for (int k = 0; k < 24; ++k) {
          int f = k * 64 + lane;
          ((float4*)&rows[(c + 1) & 1][q][f / 96][0])[f % 96] = stg[k];
        }
      }
      __syncthreads();
    }
    return;
  }

  // wave 0: dual-chain scanner
  int sbase = lane * 6;
  MasState s0 = {0.f,0.f,0.f,0.f,0.f,0.f, 0u,0u,0u,0u,0u,0u};
  MasState s1 = {0.f,0.f,0.f,0.f,0.f,0.f, 0u,0u,0u,0u,0u,0u};
  unsigned* dir0 = (unsigned*)(llbase + (size_t)(pb * 2 + 0) * T * S);
  unsigned* dir1 = (unsigned*)(llbase + (size_t)(pb * 2 + 1) * T * S);

  __syncthreads();   // matches loaders' prologue barrier
  for (int c = 0; c < NCH; ++c) {
    const float* r0 = &rows[c & 1][0][0][0];
    const float* r1 = &rows[c & 1][1][0][0];
    int t0 = c * 16;
    if (c < 24)   // t <= 383: s<=t masking active
      scan_pair16<true >(r0, r1, t0, sbase, s0, s1);
    else
      scan_pair16<false>(r0, r1, t0, sbase, s0, s1);
    if (c & 1) {
      int w = c >> 1;
      flush_dir(dir0 + (size_t)w * S + sbase, s0);
      flush_dir(dir1 + (size_t)w * S + sbase, s1);
    }
    __syncthreads();
  }
  // final partial word (chunk 74, bits r=0..15 of word 37)
  flush_dir(dir0 + (size_t)37 * S + sbase, s0);
  flush_dir(dir1 + (size_t)37 * S + sbase, s1);
}

// ---------------------------------------------------------------------------
// Kernel 3b: MAS backtrack from global word-major dirT (in ll's prefix).
// One block per batch; lane 0 runs the verified reload-flag loop.
__global__ __launch_bounds__(64) void k_bwd(
    const float* llbase, const int* __restrict__ textlen,
    const int* __restrict__ mellen, int* __restrict__ pathidx, int T, int S) {
  int b = blockIdx.x;
  int lane = threadIdx.x;
  int mel = mellen[b], txt = textlen[b];
  const unsigned* dirg = (const unsigned*)(llbase + (size_t)b * T * S);
  size_t base = (size_t)b * T;
  int k0 = T - mel;  // rows j >= mel: direction forced to 1, i stays txt-1
  for (int k = lane; k < k0; k += 64) pathidx[base + k] = txt - 1;

  if (lane == 0) {
    int i = txt - 1;
    int j = mel - 1;
    unsigned w = ~0u;
    bool reload = true;
    for (int k = k0; k < T; ++k) {
      pathidx[base + k] = i;
      if (reload) {
        int ii = (i < 0) ? i + S : i;   // JAX negative-index wrap
        ii = (ii < 0) ? 0 : ii;
        w = (ii < txt) ? dirg[(size_t)(j >> 5) * S + ii] : ~0u;  // outside mask: d=1
      }
      int d = (int)((w >> (j & 31)) & 1u);
      reload = (d == 0) | ((j & 31) == 0);
      i += d - 1;
      --j;
    }
  }
}

// ---------------------------------------------------------------------------
// Kernel 4: write attn = one_hot(path) * attnmask (overwrites the ll scratch)
__global__ __launch_bounds__(256) void k_scatter(
    float* __restrict__ attn, const int* __restrict__ pathidx,
    const int* __restrict__ textlen, const int* __restrict__ mellen,
    int B, int T, int S) {
  size_t idx = ((size_t)blockIdx.x * blockDim.x + threadIdx.x) * 4;
  size_t total = (size_t)B * T * S;
  if (idx >= total) return;
  int s = (int)(idx % S);
  size_t row = idx / S;
  int b = (int)(row / T);
  int k = (int)(row % T);
  int pi = pathidx[row];
  int mel = mellen[b], txt = textlen[b];
  float4 o = make_float4(0.f, 0.f, 0.f, 0.f);
  if (k < mel && pi >= 0 && pi < S && pi < txt && pi >= s && pi < s + 4)
    (&o.x)[pi - s] = 1.f;
  *(float4*)(attn + idx) = o;
}

// ---------------------------------------------------------------------------
// Kernel 5: rowsum[b,k] = sum_c (latent - aligned)^2 ; aligned = mean[path] or 0
__global__ __launch_bounds__(256) void k_rowloss(
    const float* __restrict__ latent, const float* __restrict__ mean,
    const int* __restrict__ pathidx, const int* __restrict__ textlen,
    const int* __restrict__ mellen, float* __restrict__ rowsum,
    int T, int S, int C) {
  int row = blockIdx.x * 4 + (threadIdx.x >> 6);
  int lane = threadIdx.x & 63;
  int b = row / T, k = row % T;
  int pi = pathidx[row];
  int mel = mellen[b], txt = textlen[b];
  bool on = (k < mel) && (pi >= 0) && (pi < S) && (pi < txt);
  const float* L = latent + (size_t)row * C;
  const float* M = mean + ((size_t)b * S + (on ? pi : 0)) * C;
  float s = 0.f;
  for (int c = lane; c < C; c += 64) {
    float d = L[c] - (on ? M[c] : 0.f);
    s += d * d;
  }
  #pragma unroll
  for (int off = 32; off; off >>= 1) s += __shfl_down(s, off);
  if (lane == 0) rowsum[row] = s;
}

// ---------------------------------------------------------------------------
// Kernel 6: per-batch durloss (histogram + log) and nll reduction
__global__ __launch_bounds__(256) void k_batch(
    const float* __restrict__ rowsum, const int* __restrict__ pathidx,
    const float* __restrict__ logdur, const int* __restrict__ textlen,
    const int* __restrict__ mellen, float* __restrict__ nllc,
    float* __restrict__ durc, int T, int S, int C) {
  int b = blockIdx.x;
  int tid = threadIdx.x;
  __shared__ int hist[512];
  __shared__ float red[256];
  int mel = mellen[b], txt = textlen[b];
  for (int s = tid; s < S; s += 256) hist[s] = 0;
  __syncthreads();
  for (int k = tid; k < T; k += 256) {
    int pi = pathidx[(size_t)b * T + k];
    if (k < mel && pi >= 0 && pi < S && pi < txt) atomicAdd(&hist[pi], 1);
  }
  __syncthreads();
  float part = 0.f;
  for (int s = tid; s < S; s += 256) {
    float cnt = (float)hist[s];
    float gt = logf(fmaxf(cnt, 1e-5f));
    gt = (s < txt) ? gt : 0.f;
    float d = logdur[(size_t)b * S + s] - gt;
    part += d * d;
  }
  red[tid] = part; __syncthreads();
  #pragma unroll
  for (int off = 128; off; off >>= 1) {
    if (tid < off) red[tid] += red[tid + off];
    __syncthreads();
  }
  if (tid == 0) durc[b] = red[0] / (float)mel;
  __syncthreads();
  part = 0.f;
  for (int k = tid; k < T; k += 256) part += rowsum[(size_t)b * T + k];
  red[tid] = part; __syncthreads();
  #pragma unroll
  for (int off = 128; off; off >>= 1) {
    if (tid < off) red[tid] += red[tid + off];
    __syncthreads();
  }
  if (tid == 0) nllc[b] = 0.5f * (LOG2PI + red[0]) / ((float)mel * (float)C);
}

// ---------------------------------------------------------------------------
// Kernel 7: loss = mean(nllc) + mean(durc)
__global__ __launch_bounds__(64) void k_final(
    const float* __restrict__ nllc, const float* __restrict__ durc,
    float* __restrict__ out, int B) {
  int lane = threadIdx.x;
  float v = (lane < B) ? (nllc[lane] + durc[lane]) : 0.f;
  #pragma unroll
  for (int off = 32; off; off >>= 1) v += __shfl_down(v, off);
  if (lane == 0) out[0] = v / (float)B;
}

// ---------------------------------------------------------------------------
extern "C" void kernel_launch(void* const* d_in, const int* in_sizes, int n_in,
                              void* d_out, int out_size, void* d_ws, size_t ws_size,
                              hipStream_t stream) {
  (void)n_in; (void)out_size; (void)ws_size;
  const float* latent = (const float*)d_in[0];
  const float* mean   = (const float*)d_in[1];
  const float* logdur = (const float*)d_in[2];
  const int*   textlen = (const int*)d_in[3];
  const int*   mellen  = (const int*)d_in[4];

  int B = in_sizes[3];
  int S = in_sizes[2] / B;
  int C = in_sizes[1] / (B * S);
  int T = in_sizes[0] / (B * C);

  float* out = (float*)d_out;
  float* ll = out + 1;  // reuse attn region [B*T*S] as ll scratch, overwritten later

  char* ws = (char*)d_ws;
  float* lx2    = (float*)ws;            // B*T
  float* lm2    = lx2 + (size_t)B * T;   // B*S
  int*   pathidx = (int*)(lm2 + (size_t)B * S);          // B*T
  float* rowsum  = (float*)(pathidx + (size_t)B * T);    // B*T
  float* nllc    = rowsum + (size_t)B * T;               // B
  float* durc    = nllc + B;                             // B

  k_sums<<<B * T + B * S, 64, 0, stream>>>(latent, mean, lx2, lm2, B * T, B * S, C);

  dim3 g2((T + 63) / 64, (S + 63) / 64, B);
  k_scores<<<g2, 256, 0, stream>>>(latent, mean, lx2, lm2, textlen, mellen, ll, T, S, C);

  k_fwd<<<B / 2, 192, 0, stream>>>(ll, T, S);

  k_bwd<<<B, 64, 0, stream>>>(ll, textlen, mellen, pathidx, T, S);

  size_t total = (size_t)B * T * S;
  k_scatter<<<(int)((total / 4 + 255) / 256), 256, 0, stream>>>(ll, pathidx, textlen, mellen, B, T, S);

  k_rowloss<<<(B * T) / 4, 256, 0, stream>>>(latent, mean, pathidx, textlen, mellen, rowsum, T, S, C);

  k_batch<<<B, 256, 0, stream>>>(rowsum, pathidx, logdur, textlen, mellen, nllc, durc, T, S, C);

  k_final<<<1, 64, 0, stream>>>(nllc, durc, out, B);
}

// Round 13
// 347.423 us; speedup vs baseline: 1.2666x; 1.2666x over previous
//
#include <hip/hip_runtime.h>
#include <math.h>

#define LOG2PI 1.8378770664093453f
#define F32MIN (-3.4028234663852886e38f)
#define SMAX 384       // S (lane math assumes 384 = 64 lanes * 6 cols)
#define RST 388        // padded LDS row stride in floats (1552B: rows differ by 16B mod 128B)
#define NW 38          // direction words per column = ceil(1200/32)

// ---------------------------------------------------------------------------
// Kernel 1: row sums of squares  lx2[b,t] = sum_c latent^2, lm2[b,s] = sum_c mean^2
__global__ __launch_bounds__(64) void k_sums(
    const float* __restrict__ latent, const float* __restrict__ mean,
    float* __restrict__ lx2, float* __restrict__ lm2, int BT, int BS, int C) {
  int row = blockIdx.x;
  int lane = threadIdx.x;
  const float* src;
  float* dst;
  if (row < BT) { src = latent + (size_t)row * C; dst = lx2 + row; }
  else          { src = mean + (size_t)(row - BT) * C; dst = lm2 + (row - BT); }
  float s = 0.f;
  for (int c = lane; c < C; c += 64) { float v = src[c]; s += v * v; }
  #pragma unroll
  for (int off = 32; off; off >>= 1) s += __shfl_down(s, off);
  if (lane == 0) *dst = s;
}

// ---------------------------------------------------------------------------
// Kernel 2: ll[b,t,s] = -0.5*(LOG2PI + lx2 - 2*dot + lm2) * attnmask
__global__ __launch_bounds__(256) void k_scores(
    const float* __restrict__ latent, const float* __restrict__ mean,
    const float* __restrict__ lx2, const float* __restrict__ lm2,
    const int* __restrict__ textlen, const int* __restrict__ mellen,
    float* __restrict__ ll, int T, int S, int C) {
  int b  = blockIdx.z;
  int t0 = blockIdx.x * 64;
  int s0 = blockIdx.y * 64;
  int mel = mellen[b], txt = textlen[b];
  int tid = threadIdx.x;
  int ty = tid >> 4, tx = tid & 15;
  float* out = ll + ((size_t)b * T + t0) * S + s0;

  if (t0 >= mel || s0 >= txt) {
    float4 z = make_float4(0.f, 0.f, 0.f, 0.f);
    #pragma unroll
    for (int i = 0; i < 4; ++i) {
      int tl = ty * 4 + i;
      if (t0 + tl < T) *(float4*)(out + (size_t)tl * S + tx * 4) = z;
    }
    return;
  }

  __shared__ float At[16][64];
  __shared__ float Bt[16][64];
  float acc[4][4] = {};

  const float* Ab = latent + ((size_t)b * T + t0) * C;
  const float* Bb = mean + ((size_t)b * S + s0) * C;

  for (int kk = 0; kk < C; kk += 16) {
    int r  = tid >> 2;
    int cg = tid & 3;
    float4 a = (t0 + r < T) ? *(const float4*)(Ab + (size_t)r * C + kk + cg * 4)
                            : make_float4(0.f, 0.f, 0.f, 0.f);
    float4 bm = *(const float4*)(Bb + (size_t)r * C + kk + cg * 4);
    At[cg * 4 + 0][r] = a.x;  At[cg * 4 + 1][r] = a.y;
    At[cg * 4 + 2][r] = a.z;  At[cg * 4 + 3][r] = a.w;
    Bt[cg * 4 + 0][r] = bm.x; Bt[cg * 4 + 1][r] = bm.y;
    Bt[cg * 4 + 2][r] = bm.z; Bt[cg * 4 + 3][r] = bm.w;
    __syncthreads();
    #pragma unroll
    for (int k = 0; k < 16; ++k) {
      float4 a4 = *(const float4*)&At[k][ty * 4];
      float4 b4 = *(const float4*)&Bt[k][tx * 4];
      float av[4] = {a4.x, a4.y, a4.z, a4.w};
      float bv[4] = {b4.x, b4.y, b4.z, b4.w};
      #pragma unroll
      for (int i = 0; i < 4; ++i)
        #pragma unroll
        for (int j = 0; j < 4; ++j)
          acc[i][j] = fmaf(av[i], bv[j], acc[i][j]);
    }
    __syncthreads();
  }

  #pragma unroll
  for (int i = 0; i < 4; ++i) {
    int t = t0 + ty * 4 + i;
    if (t >= T) continue;
    float lx = lx2[(size_t)b * T + t];
    float4 o;
    float* po = &o.x;
    #pragma unroll
    for (int j = 0; j < 4; ++j) {
      int s = s0 + tx * 4 + j;
      float d = lx - 2.f * acc[i][j] + lm2[(size_t)b * S + s];
      float v = -0.5f * (LOG2PI + d);
      po[j] = (t < mel && s < txt) ? v : 0.f;
    }
    *(float4*)(out + (size_t)(ty * 4 + i) * S + tx * 4) = o;
  }
}

// ---------------------------------------------------------------------------
// DPP wave_shr:1 — lane l gets lane l-1's value, lane 0 gets -inf. Pure VALU.
__device__ __forceinline__ float dpp_shr1_neginf(float x) {
  int r = __builtin_amdgcn_update_dpp(
      __float_as_int(-INFINITY), __float_as_int(x),
      0x138 /*wave_shr:1*/, 0xf, 0xf, false);
  return __int_as_float(r);
}

// One MAS step — VCC-free (R10/R12-verified math). Max via v_max_f32; direction
// bit via sign(p - q) (p>=q <=> signbit(p-q)==0 here; ties give +0 and -0
// never arises since ll is exactly 0 or <= -0.9). Inverted bits accumulated,
// flush writes ~n. r (bit index) is wave-uniform.
template <bool MASKED>
__device__ __forceinline__ void mas_step(
    int t, int sbase, int r, const float2 A0, const float2 A1, const float2 A2,
    float& p0, float& p1, float& p2, float& p3, float& p4, float& p5,
    unsigned& n0, unsigned& n1, unsigned& n2, unsigned& n3, unsigned& n4,
    unsigned& n5) {
  float l0 = A0.x, l1 = A0.y, l2 = A1.x, l3 = A1.y, l4 = A2.x, l5 = A2.y;
  float pm1 = dpp_shr1_neginf(p5);
  unsigned s0b = __float_as_uint(p0 - pm1) >> 31;
  unsigned s1b = __float_as_uint(p1 - p0)  >> 31;
  unsigned s2b = __float_as_uint(p2 - p1)  >> 31;
  unsigned s3b = __float_as_uint(p3 - p2)  >> 31;
  unsigned s4b = __float_as_uint(p4 - p3)  >> 31;
  unsigned s5b = __float_as_uint(p5 - p4)  >> 31;
  n0 |= s0b << r; n1 |= s1b << r; n2 |= s2b << r;
  n3 |= s3b << r; n4 |= s4b << r; n5 |= s5b << r;
  float v0 = fmaxf(p0, pm1) + l0;
  float v1 = fmaxf(p1, p0) + l1;
  float v2 = fmaxf(p2, p1) + l2;
  float v3 = fmaxf(p3, p2) + l3;
  float v4 = fmaxf(p4, p3) + l4;
  float v5 = fmaxf(p5, p4) + l5;
  if (MASKED) {
    p0 = (sbase + 0 <= t) ? v0 : F32MIN;
    p1 = (sbase + 1 <= t) ? v1 : F32MIN;
    p2 = (sbase + 2 <= t) ? v2 : F32MIN;
    p3 = (sbase + 3 <= t) ? v3 : F32MIN;
    p4 = (sbase + 4 <= t) ? v4 : F32MIN;
    p5 = (sbase + 5 <= t) ? v5 : F32MIN;
  } else {
    p0 = v0; p1 = v1; p2 = v2; p3 = v3; p4 = v4; p5 = v5;
  }
}

// ---------------------------------------------------------------------------
// Consumer: scan ROWS steps of one LDS chunk. Depth-4 named register ring,
// unroll-4 rolled loop, ONE spread row-read per step (R9 cadence — avoids
// R10's grouped same-bank-phase reads). Each row's reads are issued 4 steps
// (~280 cy) before use, so the in-order lgkmcnt wait for the oldest row is
// satisfied long before consumption.
template <bool MASKED, int ROWS>
__device__ __forceinline__ void scan_chunk_lds(
    const float* __restrict__ rcur, int t0, int sbase,
    float& p0, float& p1, float& p2, float& p3, float& p4, float& p5,
    unsigned* __restrict__ dirT, int cw) {
  unsigned n0 = 0, n1 = 0, n2 = 0, n3 = 0, n4 = 0, n5 = 0;
  const float2* q = (const float2*)(rcur + sbase);   // row stride = RST/2 float2
  float2 A0 = q[0 * (RST / 2)], A1 = q[0 * (RST / 2) + 1], A2 = q[0 * (RST / 2) + 2];
  float2 B0 = q[1 * (RST / 2)], B1 = q[1 * (RST / 2) + 1], B2 = q[1 * (RST / 2) + 2];
  float2 C0 = q[2 * (RST / 2)], C1 = q[2 * (RST / 2) + 1], C2 = q[2 * (RST / 2) + 2];
  float2 D0 = q[3 * (RST / 2)], D1 = q[3 * (RST / 2) + 1], D2 = q[3 * (RST / 2) + 2];
  #pragma unroll 1
  for (int r = 0; r < ROWS; r += 4) {
    mas_step<MASKED>(t0 + r, sbase, r, A0, A1, A2,
                     p0, p1, p2, p3, p4, p5, n0, n1, n2, n3, n4, n5);
    {
      int rn = (r + 4 < ROWS) ? r + 4 : ROWS - 1;   // clamp: dummy in-bounds read
      const float2* p = q + (size_t)rn * (RST / 2);
      A0 = p[0]; A1 = p[1]; A2 = p[2];
    }
    mas_step<MASKED>(t0 + r + 1, sbase, r + 1, B0, B1, B2,
                     p0, p1, p2, p3, p4, p5, n0, n1, n2, n3, n4, n5);
    {
      int rn = (r + 5 < ROWS) ? r + 5 : ROWS - 1;
      const float2* p = q + (size_t)rn * (RST / 2);
      B0 = p[0]; B1 = p[1]; B2 = p[2];
    }
    mas_step<MASKED>(t0 + r + 2, sbase, r + 2, C0, C1, C2,
                     p0, p1, p2, p3, p4, p5, n0, n1, n2, n3, n4, n5);
    {
      int rn = (r + 6 < ROWS) ? r + 6 : ROWS - 1;
      const float2* p = q + (size_t)rn * (RST / 2);
      C0 = p[0]; C1 = p[1]; C2 = p[2];
    }
    mas_step<MASKED>(t0 + r + 3, sbase, r + 3, D0, D1, D2,
                     p0, p1, p2, p3, p4, p5, n0, n1, n2, n3, n4, n5);
    {
      int rn = (r + 7 < ROWS) ? r + 7 : ROWS - 1;
      const float2* p = q + (size_t)rn * (RST / 2);
      D0 = p[0]; D1 = p[1]; D2 = p[2];
    }
  }
  unsigned* dcol = dirT + (unsigned)sbase * NW + cw;
  dcol[0] = ~n0; dcol[NW] = ~n1; dcol[2 * NW] = ~n2;
  dcol[3 * NW] = ~n3; dcol[4 * NW] = ~n4; dcol[5 * NW] = ~n5;
}

// ---------------------------------------------------------------------------
// Kernel 3: MAS forward scan + backtrack. One block (4 waves) per batch.
// Wave 0: depth-4 VCC-free rolled scan loop from LDS. Waves 1-3: double-buffer
// the next 32-row ll chunk global->reg->LDS (padded row stride RST).
// Direction bits packed per-lane into u32 accumulators, one 6-word LDS flush
// per chunk into column-major dirT. Backtrack: verified reload-flag loop.
// Assumes S == 384, T == 37*32 + 16.
__global__ __launch_bounds__(256, 1) void k_scan(
    const float* __restrict__ ll, const int* __restrict__ textlen,
    const int* __restrict__ mellen, int* __restrict__ pathidx, int T, int S) {
  int b = blockIdx.x;
  int tid = threadIdx.x;
  int lane = tid & 63;
  __shared__ float rows[2][32][RST];        // 99328 B (padded rows)
  __shared__ unsigned dirT[SMAX * NW];      // 58368 B, column-major bit-pack

  const float* llb = ll + (size_t)b * T * S;
  int mel = mellen[b], txt = textlen[b];
  int sbase = lane * 6;
  int nfull = T / 32;                        // 37
  int nch = (T + 31) / 32;                   // 38 (16-row tail)
  float p0 = 0.f, p1 = 0.f, p2 = 0.f, p3 = 0.f, p4 = 0.f, p5 = 0.f;

  // prologue: loader waves fill chunk 0 (32*384 floats = 3072 float4, 192x16)
  if (tid >= 64) {
    int lid = tid - 64;
    const float4* g = (const float4*)llb;
    #pragma unroll
    for (int k = 0; k < 16; ++k) {
      int f = k * 192 + lid;                 // flat float4 index over [32][96]
      ((float4*)&rows[0][f / 96][0])[f % 96] = g[f];
    }
  }
  __syncthreads();

  for (int c = 0; c < nch; ++c) {
    if (tid >= 64) {
      int nxt = c + 1;
      if (nxt < nch) {
        int lid = tid - 64;
        const float4* g = (const float4*)(llb + (size_t)nxt * 32 * S);
        if (nxt < nfull) {
          float4 stg[16];
          #pragma unroll
          for (int k = 0; k < 16; ++k) stg[k] = g[k * 192 + lid];
          #pragma unroll
          for (int k = 0; k < 16; ++k) {
            int f = k * 192 + lid;
            ((float4*)&rows[nxt & 1][f / 96][0])[f % 96] = stg[k];
          }
        } else {
          float4 stg[8];
          #pragma unroll
          for (int k = 0; k < 8; ++k) stg[k] = g[k * 192 + lid];
          #pragma unroll
          for (int k = 0; k < 8; ++k) {
            int f = k * 192 + lid;
            ((float4*)&rows[nxt & 1][f / 96][0])[f % 96] = stg[k];
          }
        }
      }
    } else {
      const float* rc = &rows[c & 1][0][0];
      int t0 = c * 32;
      if (c < nfull) {
        if (t0 < S)   // s<=t masking only relevant while t can be < s_max
          scan_chunk_lds<true, 32>(rc, t0, sbase, p0, p1, p2, p3, p4, p5, dirT, c);
        else
          scan_chunk_lds<false, 32>(rc, t0, sbase, p0, p1, p2, p3, p4, p5, dirT, c);
      } else {
        scan_chunk_lds<false, 16>(rc, t0, sbase, p0, p1, p2, p3, p4, p5, dirT, c);
      }
    }
    __syncthreads();
  }

  if (tid >= 64) return;

  size_t base = (size_t)b * T;
  int k0 = T - mel;  // rows j >= mel: direction forced to 1, i stays txt-1
  for (int k = lane; k < k0; k += 64) pathidx[base + k] = txt - 1;

  if (lane == 0) {
    // Verified backtrack: reload cached word only when the path moved (d==0)
    // or j crossed a 32-row word boundary.
    int i = txt - 1;
    int j = mel - 1;
    unsigned w = ~0u;
    bool reload = true;
    for (int k = k0; k < T; ++k) {
      pathidx[base + k] = i;
      if (reload) {
        int ii = (i < 0) ? i + S : i;   // JAX negative-index wrap
        ii = (ii < 0) ? 0 : ii;
        w = (ii < txt) ? dirT[ii * NW + (j >> 5)] : ~0u;  // outside mask: d=1
      }
      int d = (int)((w >> (j & 31)) & 1u);
      reload = (d == 0) | ((j & 31) == 0);
      i += d - 1;
      --j;
    }
  }
}

// ---------------------------------------------------------------------------
// Kernel 4: write attn = one_hot(path) * attnmask (overwrites the ll scratch)
__global__ __launch_bounds__(256) void k_scatter(
    float* __restrict__ attn, const int* __restrict__ pathidx,
    const int* __restrict__ textlen, const int* __restrict__ mellen,
    int B, int T, int S) {
  size_t idx = ((size_t)blockIdx.x * blockDim.x + threadIdx.x) * 4;
  size_t total = (size_t)B * T * S;
  if (idx >= total) return;
  int s = (int)(idx % S);
  size_t row = idx / S;
  int b = (int)(row / T);
  int k = (int)(row % T);
  int pi = pathidx[row];
  int mel = mellen[b], txt = textlen[b];
  float4 o = make_float4(0.f, 0.f, 0.f, 0.f);
  if (k < mel && pi >= 0 && pi < S && pi < txt && pi >= s && pi < s + 4)
    (&o.x)[pi - s] = 1.f;
  *(float4*)(attn + idx) = o;
}

// ---------------------------------------------------------------------------
// Kernel 5: rowsum[b,k] = sum_c (latent - aligned)^2 ; aligned = mean[path] or 0
__global__ __launch_bounds__(256) void k_rowloss(
    const float* __restrict__ latent, const float* __restrict__ mean,
    const int* __restrict__ pathidx, const int* __restrict__ textlen,
    const int* __restrict__ mellen, float* __restrict__ rowsum,
    int T, int S, int C) {
  int row = blockIdx.x * 4 + (threadIdx.x >> 6);
  int lane = threadIdx.x & 63;
  int b = row / T, k = row % T;
  int pi = pathidx[row];
  int mel = mellen[b], txt = textlen[b];
  bool on = (k < mel) && (pi >= 0) && (pi < S) && (pi < txt);
  const float* L = latent + (size_t)row * C;
  const float* M = mean + ((size_t)b * S + (on ? pi : 0)) * C;
  float s = 0.f;
  for (int c = lane; c < C; c += 64) {
    float d = L[c] - (on ? M[c] : 0.f);
    s += d * d;
  }
  #pragma unroll
  for (int off = 32; off; off >>= 1) s += __shfl_down(s, off);
  if (lane == 0) rowsum[row] = s;
}

// ---------------------------------------------------------------------------
// Kernel 6: per-batch durloss (histogram + log) and nll reduction
__global__ __launch_bounds__(256) void k_batch(
    const float* __restrict__ rowsum, const int* __restrict__ pathidx,
    const float* __restrict__ logdur, const int* __restrict__ textlen,
    const int* __restrict__ mellen, float* __restrict__ nllc,
    float* __restrict__ durc, int T, int S, int C) {
  int b = blockIdx.x;
  int tid = threadIdx.x;
  __shared__ int hist[512];
  __shared__ float red[256];
  int mel = mellen[b], txt = textlen[b];
  for (int s = tid; s < S; s += 256) hist[s] = 0;
  __syncthreads();
  for (int k = tid; k < T; k += 256) {
    int pi = pathidx[(size_t)b * T + k];
    if (k < mel && pi >= 0 && pi < S && pi < txt) atomicAdd(&hist[pi], 1);
  }
  __syncthreads();
  float part = 0.f;
  for (int s = tid; s < S; s += 256) {
    float cnt = (float)hist[s];
    float gt = logf(fmaxf(cnt, 1e-5f));
    gt = (s < txt) ? gt : 0.f;
    float d = logdur[(size_t)b * S + s] - gt;
    part += d * d;
  }
  red[tid] = part; __syncthreads();
  #pragma unroll
  for (int off = 128; off; off >>= 1) {
    if (tid < off) red[tid] += red[tid + off];
    __syncthreads();
  }
  if (tid == 0) durc[b] = red[0] / (float)mel;
  __syncthreads();
  part = 0.f;
  for (int k = tid; k < T; k += 256) part += rowsum[(size_t)b * T + k];
  red[tid] = part; __syncthreads();
  #pragma unroll
  for (int off = 128; off; off >>= 1) {
    if (tid < off) red[tid] += red[tid + off];
    __syncthreads();
  }
  if (tid == 0) nllc[b] = 0.5f * (LOG2PI + red[0]) / ((float)mel * (float)C);
}

// ---------------------------------------------------------------------------
// Kernel 7: loss = mean(nllc) + mean(durc)
__global__ __launch_bounds__(64) void k_final(
    const float* __restrict__ nllc, const float* __restrict__ durc,
    float* __restrict__ out, int B) {
  int lane = threadIdx.x;
  float v = (lane < B) ? (nllc[lane] + durc[lane]) : 0.f;
  #pragma unroll
  for (int off = 32; off; off >>= 1) v += __shfl_down(v, off);
  if (lane == 0) out[0] = v / (float)B;
}

// ---------------------------------------------------------------------------
extern "C" void kernel_launch(void* const* d_in, const int* in_sizes, int n_in,
                              void* d_out, int out_size, void* d_ws, size_t ws_size,
                              hipStream_t stream) {
  (void)n_in; (void)out_size; (void)ws_size;
  const float* latent = (const float*)d_in[0];
  const float* mean   = (const float*)d_in[1];
  const float* logdur = (const float*)d_in[2];
  const int*   textlen = (const int*)d_in[3];
  const int*   mellen  = (const int*)d_in[4];

  int B = in_sizes[3];
  int S = in_sizes[2] / B;
  int C = in_sizes[1] / (B * S);
  int T = in_sizes[0] / (B * C);

  float* out = (float*)d_out;
  float* ll = out + 1;  // reuse attn region [B*T*S] as ll scratch, overwritten later

  char* ws = (char*)d_ws;
  float* lx2    = (float*)ws;            // B*T
  float* lm2    = lx2 + (size_t)B * T;   // B*S
  int*   pathidx = (int*)(lm2 + (size_t)B * S);          // B*T
  float* rowsum  = (float*)(pathidx + (size_t)B * T);    // B*T
  float* nllc    = rowsum + (size_t)B * T;               // B
  float* durc    = nllc + B;                             // B

  k_sums<<<B * T + B * S, 64, 0, stream>>>(latent, mean, lx2, lm2, B * T, B * S, C);

  dim3 g2((T + 63) / 64, (S + 63) / 64, B);
  k_scores<<<g2, 256, 0, stream>>>(latent, mean, lx2, lm2, textlen, mellen, ll, T, S, C);

  k_scan<<<B, 256, 0, stream>>>(ll, textlen, mellen, pathidx, T, S);

  size_t total = (size_t)B * T * S;
  k_scatter<<<(int)((total / 4 + 255) / 256), 256, 0, stream>>>(ll, pathidx, textlen, mellen, B, T, S);

  k_rowloss<<<(B * T) / 4, 256, 0, stream>>>(latent, mean, pathidx, textlen, mellen, rowsum, T, S, C);

  k_batch<<<B, 256, 0, stream>>>(rowsum, pathidx, logdur, textlen, mellen, nllc, durc, T, S, C);

  k_final<<<1, 64, 0, stream>>>(nllc, durc, out, B);
}

// Round 14
// 321.105 us; speedup vs baseline: 1.3705x; 1.0820x over previous
//
#include <hip/hip_runtime.h>
#include <math.h>

#define LOG2PI 1.8378770664093453f
#define F32MIN (-3.4028234663852886e38f)
#define SMAX 384       // S (lane math assumes 384 = 64 lanes * 6 cols)
#define RST 388        // padded LDS row stride in floats
#define NW 38          // direction words per column = ceil(1200/32)

// ---------------------------------------------------------------------------
// Kernel 1: row sums of squares  lx2[b,t] = sum_c latent^2, lm2[b,s] = sum_c mean^2
__global__ __launch_bounds__(64) void k_sums(
    const float* __restrict__ latent, const float* __restrict__ mean,
    float* __restrict__ lx2, float* __restrict__ lm2, int BT, int BS, int C) {
  int row = blockIdx.x;
  int lane = threadIdx.x;
  const float* src;
  float* dst;
  if (row < BT) { src = latent + (size_t)row * C; dst = lx2 + row; }
  else          { src = mean + (size_t)(row - BT) * C; dst = lm2 + (row - BT); }
  float s = 0.f;
  for (int c = lane; c < C; c += 64) { float v = src[c]; s += v * v; }
  #pragma unroll
  for (int off = 32; off; off >>= 1) s += __shfl_down(s, off);
  if (lane == 0) *dst = s;
}

// ---------------------------------------------------------------------------
// Kernel 2: ll[b,t,s] = -0.5*(LOG2PI + lx2 - 2*dot + lm2) * attnmask
// Masked-out tiles are SKIPPED entirely (no zero write): nothing downstream
// reads them — the scan stops at mel, columns >= txt only propagate rightward
// and their direction bits are never read, and tiles wholly s>t are per-cell
// FMIN'd by the scan's masking.
__global__ __launch_bounds__(256) void k_scores(
    const float* __restrict__ latent, const float* __restrict__ mean,
    const float* __restrict__ lx2, const float* __restrict__ lm2,
    const int* __restrict__ textlen, const int* __restrict__ mellen,
    float* __restrict__ ll, int T, int S, int C) {
  int b  = blockIdx.z;
  int t0 = blockIdx.x * 64;
  int s0 = blockIdx.y * 64;
  int mel = mellen[b], txt = textlen[b];
  int tid = threadIdx.x;
  int ty = tid >> 4, tx = tid & 15;
  float* out = ll + ((size_t)b * T + t0) * S + s0;

  if (t0 >= mel || s0 >= txt || s0 > t0 + 63) return;

  __shared__ float At[16][64];
  __shared__ float Bt[16][64];
  float acc[4][4] = {};

  const float* Ab = latent + ((size_t)b * T + t0) * C;
  const float* Bb = mean + ((size_t)b * S + s0) * C;

  for (int kk = 0; kk < C; kk += 16) {
    int r  = tid >> 2;
    int cg = tid & 3;
    float4 a = (t0 + r < T) ? *(const float4*)(Ab + (size_t)r * C + kk + cg * 4)
                            : make_float4(0.f, 0.f, 0.f, 0.f);
    float4 bm = *(const float4*)(Bb + (size_t)r * C + kk + cg * 4);
    At[cg * 4 + 0][r] = a.x;  At[cg * 4 + 1][r] = a.y;
    At[cg * 4 + 2][r] = a.z;  At[cg * 4 + 3][r] = a.w;
    Bt[cg * 4 + 0][r] = bm.x; Bt[cg * 4 + 1][r] = bm.y;
    Bt[cg * 4 + 2][r] = bm.z; Bt[cg * 4 + 3][r] = bm.w;
    __syncthreads();
    #pragma unroll
    for (int k = 0; k < 16; ++k) {
      float4 a4 = *(const float4*)&At[k][ty * 4];
      float4 b4 = *(const float4*)&Bt[k][tx * 4];
      float av[4] = {a4.x, a4.y, a4.z, a4.w};
      float bv[4] = {b4.x, b4.y, b4.z, b4.w};
      #pragma unroll
      for (int i = 0; i < 4; ++i)
        #pragma unroll
        for (int j = 0; j < 4; ++j)
          acc[i][j] = fmaf(av[i], bv[j], acc[i][j]);
    }
    __syncthreads();
  }

  #pragma unroll
  for (int i = 0; i < 4; ++i) {
    int t = t0 + ty * 4 + i;
    if (t >= T) continue;
    float lx = lx2[(size_t)b * T + t];
    float4 o;
    float* po = &o.x;
    #pragma unroll
    for (int j = 0; j < 4; ++j) {
      int s = s0 + tx * 4 + j;
      float d = lx - 2.f * acc[i][j] + lm2[(size_t)b * S + s];
      float v = -0.5f * (LOG2PI + d);
      po[j] = (t < mel && s < txt) ? v : 0.f;
    }
    *(float4*)(out + (size_t)(ty * 4 + i) * S + tx * 4) = o;
  }
}

// ---------------------------------------------------------------------------
// DPP wave_shr:1 — lane l gets lane l-1's value, lane 0 gets -inf. Pure VALU.
__device__ __forceinline__ float dpp_shr1_neginf(float x) {
  int r = __builtin_amdgcn_update_dpp(
      __float_as_int(-INFINITY), __float_as_int(x),
      0x138 /*wave_shr:1*/, 0xf, 0xf, false);
  return __int_as_float(r);
}

// One MAS step — VCC-free (R10/R12/R13-verified math). Max via v_max_f32;
// direction bit via sign(p - q) (p>=q <=> signbit(p-q)==0 here; ties give +0
// and -0 never arises since ll is exactly 0 or <= -0.9). Inverted bits
// accumulated; flush writes ~n. r (bit index) is wave-uniform.
template <bool MASKED>
__device__ __forceinline__ void mas_step(
    int t, int sbase, int r, const float2 A0, const float2 A1, const float2 A2,
    float& p0, float& p1, float& p2, float& p3, float& p4, float& p5,
    unsigned& n0, unsigned& n1, unsigned& n2, unsigned& n3, unsigned& n4,
    unsigned& n5) {
  float l0 = A0.x, l1 = A0.y, l2 = A1.x, l3 = A1.y, l4 = A2.x, l5 = A2.y;
  float pm1 = dpp_shr1_neginf(p5);
  unsigned s0b = __float_as_uint(p0 - pm1) >> 31;
  unsigned s1b = __float_as_uint(p1 - p0)  >> 31;
  unsigned s2b = __float_as_uint(p2 - p1)  >> 31;
  unsigned s3b = __float_as_uint(p3 - p2)  >> 31;
  unsigned s4b = __float_as_uint(p4 - p3)  >> 31;
  unsigned s5b = __float_as_uint(p5 - p4)  >> 31;
  n0 |= s0b << r; n1 |= s1b << r; n2 |= s2b << r;
  n3 |= s3b << r; n4 |= s4b << r; n5 |= s5b << r;
  float v0 = fmaxf(p0, pm1) + l0;
  float v1 = fmaxf(p1, p0) + l1;
  float v2 = fmaxf(p2, p1) + l2;
  float v3 = fmaxf(p3, p2) + l3;
  float v4 = fmaxf(p4, p3) + l4;
  float v5 = fmaxf(p5, p4) + l5;
  if (MASKED) {
    p0 = (sbase + 0 <= t) ? v0 : F32MIN;
    p1 = (sbase + 1 <= t) ? v1 : F32MIN;
    p2 = (sbase + 2 <= t) ? v2 : F32MIN;
    p3 = (sbase + 3 <= t) ? v3 : F32MIN;
    p4 = (sbase + 4 <= t) ? v4 : F32MIN;
    p5 = (sbase + 5 <= t) ? v5 : F32MIN;
  } else {
    p0 = v0; p1 = v1; p2 = v2; p3 = v3; p4 = v4; p5 = v5;
  }
}

// ---------------------------------------------------------------------------
// Consumer: scan ROWS steps of one LDS chunk. Depth-2 named-register cadence
// (R9's proven pattern — depth-4 regresses via LDS queueing, R10/R13).
template <bool MASKED, int ROWS>
__device__ __forceinline__ void scan_chunk_lds(
    const float* __restrict__ rcur, int t0, int sbase,
    float& p0, float& p1, float& p2, float& p3, float& p4, float& p5,
    unsigned* __restrict__ dirT, int cw) {
  unsigned n0 = 0, n1 = 0, n2 = 0, n3 = 0, n4 = 0, n5 = 0;
  const float2* q = (const float2*)(rcur + sbase);   // row stride = RST/2 float2
  float2 A0 = q[0], A1 = q[1], A2 = q[2];
  #pragma unroll 1
  for (int r = 0; r < ROWS; r += 2) {
    const float2* qb = q + (size_t)(r + 1) * (RST / 2);
    float2 B0 = qb[0], B1 = qb[1], B2 = qb[2];
    mas_step<MASKED>(t0 + r, sbase, r, A0, A1, A2,
                     p0, p1, p2, p3, p4, p5, n0, n1, n2, n3, n4, n5);
    int rn = (r + 2 < ROWS) ? (r + 2) : (ROWS - 1);   // clamp: dummy in-bounds read
    const float2* qa = q + (size_t)rn * (RST / 2);
    A0 = qa[0]; A1 = qa[1]; A2 = qa[2];
    mas_step<MASKED>(t0 + r + 1, sbase, r + 1, B0, B1, B2,
                     p0, p1, p2, p3, p4, p5, n0, n1, n2, n3, n4, n5);
  }
  unsigned* dcol = dirT + (unsigned)sbase * NW + cw;
  dcol[0] = ~n0; dcol[NW] = ~n1; dcol[2 * NW] = ~n2;
  dcol[3 * NW] = ~n3; dcol[4 * NW] = ~n4; dcol[5 * NW] = ~n5;
}

// ---------------------------------------------------------------------------
// Kernel 3: MAS forward scan + backtrack. One block (4 waves) per batch.
// Forward scan runs only to ceil(mel/32) chunks — rows t >= mel are never
// consumed (backtrack reads direction bits only for j < mel; bit positions
// >= mel inside the final word are never extracted). Loaders share the same
// uniform cap, so barrier counts match.
// Assumes S == 384, T == 37*32 + 16.
__global__ __launch_bounds__(256, 1) void k_scan(
    const float* __restrict__ ll, const int* __restrict__ textlen,
    const int* __restrict__ mellen, int* __restrict__ pathidx, int T, int S) {
  int b = blockIdx.x;
  int tid = threadIdx.x;
  int lane = tid & 63;
  __shared__ float rows[2][32][RST];        // 99328 B (padded rows)
  __shared__ unsigned dirT[SMAX * NW];      // 58368 B, column-major bit-pack

  const float* llb = ll + (size_t)b * T * S;
  int mel = mellen[b], txt = textlen[b];
  int sbase = lane * 6;
  int nfull = T / 32;                        // 37
  int nch = (T + 31) / 32;                   // 38 (16-row tail)
  int nchb = (mel + 31) / 32;                // chunks actually needed
  if (nchb > nch) nchb = nch;
  float p0 = 0.f, p1 = 0.f, p2 = 0.f, p3 = 0.f, p4 = 0.f, p5 = 0.f;

  // prologue: loader waves fill chunk 0 (32*384 floats = 3072 float4, 192x16)
  if (tid >= 64) {
    int lid = tid - 64;
    const float4* g = (const float4*)llb;
    #pragma unroll
    for (int k = 0; k < 16; ++k) {
      int f = k * 192 + lid;                 // flat float4 index over [32][96]
      ((float4*)&rows[0][f / 96][0])[f % 96] = g[f];
    }
  }
  __syncthreads();

  for (int c = 0; c < nchb; ++c) {
    if (tid >= 64) {
      int nxt = c + 1;
      if (nxt < nchb) {
        int lid = tid - 64;
        const float4* g = (const float4*)(llb + (size_t)nxt * 32 * S);
        if (nxt < nfull) {
          float4 stg[16];
          #pragma unroll
          for (int k = 0; k < 16; ++k) stg[k] = g[k * 192 + lid];
          #pragma unroll
          for (int k = 0; k < 16; ++k) {
            int f = k * 192 + lid;
            ((float4*)&rows[nxt & 1][f / 96][0])[f % 96] = stg[k];
          }
        } else {
          float4 stg[8];
          #pragma unroll
          for (int k = 0; k < 8; ++k) stg[k] = g[k * 192 + lid];
          #pragma unroll
          for (int k = 0; k < 8; ++k) {
            int f = k * 192 + lid;
            ((float4*)&rows[nxt & 1][f / 96][0])[f % 96] = stg[k];
          }
        }
      }
    } else {
      const float* rc = &rows[c & 1][0][0];
      int t0 = c * 32;
      if (c < 12)        // chunks 0..11: t <= 383, per-cell s<=t masking
        scan_chunk_lds<true, 32>(rc, t0, sbase, p0, p1, p2, p3, p4, p5, dirT, c);
      else if (c < nfull)
        scan_chunk_lds<false, 32>(rc, t0, sbase, p0, p1, p2, p3, p4, p5, dirT, c);
      else
        scan_chunk_lds<false, 16>(rc, t0, sbase, p0, p1, p2, p3, p4, p5, dirT, c);
    }
    __syncthreads();
  }

  if (tid >= 64) return;

  size_t base = (size_t)b * T;
  int k0 = T - mel;  // rows j >= mel: direction forced to 1, i stays txt-1
  for (int k = lane; k < k0; k += 64) pathidx[base + k] = txt - 1;

  if (lane == 0) {
    // Verified backtrack: reload cached word only when the path moved (d==0)
    // or j crossed a 32-row word boundary.
    int i = txt - 1;
    int j = mel - 1;
    unsigned w = ~0u;
    bool reload = true;
    for (int k = k0; k < T; ++k) {
      pathidx[base + k] = i;
      if (reload) {
        int ii = (i < 0) ? i + S : i;   // JAX negative-index wrap
        ii = (ii < 0) ? 0 : ii;
        w = (ii < txt) ? dirT[ii * NW + (j >> 5)] : ~0u;  // outside mask: d=1
      }
      int d = (int)((w >> (j & 31)) & 1u);
      reload = (d == 0) | ((j & 31) == 0);
      i += d - 1;
      --j;
    }
  }
}

// ---------------------------------------------------------------------------
// Kernel 4: write attn = one_hot(path) * attnmask (overwrites the ll scratch)
__global__ __launch_bounds__(256) void k_scatter(
    float* __restrict__ attn, const int* __restrict__ pathidx,
    const int* __restrict__ textlen, const int* __restrict__ mellen,
    int B, int T, int S) {
  size_t idx = ((size_t)blockIdx.x * blockDim.x + threadIdx.x) * 4;
  size_t total = (size_t)B * T * S;
  if (idx >= total) return;
  int s = (int)(idx % S);
  size_t row = idx / S;
  int b = (int)(row / T);
  int k = (int)(row % T);
  int pi = pathidx[row];
  int mel = mellen[b], txt = textlen[b];
  float4 o = make_float4(0.f, 0.f, 0.f, 0.f);
  if (k < mel && pi >= 0 && pi < S && pi < txt && pi >= s && pi < s + 4)
    (&o.x)[pi - s] = 1.f;
  *(float4*)(attn + idx) = o;
}

// ---------------------------------------------------------------------------
// Kernel 5: rowsum[b,k] = sum_c (latent - aligned)^2 ; aligned = mean[path] or 0
__global__ __launch_bounds__(256) void k_rowloss(
    const float* __restrict__ latent, const float* __restrict__ mean,
    const int* __restrict__ pathidx, const int* __restrict__ textlen,
    const int* __restrict__ mellen, float* __restrict__ rowsum,
    int T, int S, int C) {
  int row = blockIdx.x * 4 + (threadIdx.x >> 6);
  int lane = threadIdx.x & 63;
  int b = row / T, k = row % T;
  int pi = pathidx[row];
  int mel = mellen[b], txt = textlen[b];
  bool on = (k < mel) && (pi >= 0) && (pi < S) && (pi < txt);
  const float* L = latent + (size_t)row * C;
  const float* M = mean + ((size_t)b * S + (on ? pi : 0)) * C;
  float s = 0.f;
  for (int c = lane; c < C; c += 64) {
    float d = L[c] - (on ? M[c] : 0.f);
    s += d * d;
  }
  #pragma unroll
  for (int off = 32; off; off >>= 1) s += __shfl_down(s, off);
  if (lane == 0) rowsum[row] = s;
}

// ---------------------------------------------------------------------------
// Kernel 6: per-batch durloss (histogram + log) and nll reduction
__global__ __launch_bounds__(256) void k_batch(
    const float* __restrict__ rowsum, const int* __restrict__ pathidx,
    const float* __restrict__ logdur, const int* __restrict__ textlen,
    const int* __restrict__ mellen, float* __restrict__ nllc,
    float* __restrict__ durc, int T, int S, int C) {
  int b = blockIdx.x;
  int tid = threadIdx.x;
  __shared__ int hist[512];
  __shared__ float red[256];
  int mel = mellen[b], txt = textlen[b];
  for (int s = tid; s < S; s += 256) hist[s] = 0;
  __syncthreads();
  for (int k = tid; k < T; k += 256) {
    int pi = pathidx[(size_t)b * T + k];
    if (k < mel && pi >= 0 && pi < S && pi < txt) atomicAdd(&hist[pi], 1);
  }
  __syncthreads();
  float part = 0.f;
  for (int s = tid; s < S; s += 256) {
    float cnt = (float)hist[s];
    float gt = logf(fmaxf(cnt, 1e-5f));
    gt = (s < txt) ? gt : 0.f;
    float d = logdur[(size_t)b * S + s] - gt;
    part += d * d;
  }
  red[tid] = part; __syncthreads();
  #pragma unroll
  for (int off = 128; off; off >>= 1) {
    if (tid < off) red[tid] += red[tid + off];
    __syncthreads();
  }
  if (tid == 0) durc[b] = red[0] / (float)mel;
  __syncthreads();
  part = 0.f;
  for (int k = tid; k < T; k += 256) part += rowsum[(size_t)b * T + k];
  red[tid] = part; __syncthreads();
  #pragma unroll
  for (int off = 128; off; off >>= 1) {
    if (tid < off) red[tid] += red[tid + off];
    __syncthreads();
  }
  if (tid == 0) nllc[b] = 0.5f * (LOG2PI + red[0]) / ((float)mel * (float)C);
}

// ---------------------------------------------------------------------------
// Kernel 7: loss = mean(nllc) + mean(durc)
__global__ __launch_bounds__(64) void k_final(
    const float* __restrict__ nllc, const float* __restrict__ durc,
    float* __restrict__ out, int B) {
  int lane = threadIdx.x;
  float v = (lane < B) ? (nllc[lane] + durc[lane]) : 0.f;
  #pragma unroll
  for (int off = 32; off; off >>= 1) v += __shfl_down(v, off);
  if (lane == 0) out[0] = v / (float)B;
}

// ---------------------------------------------------------------------------
extern "C" void kernel_launch(void* const* d_in, const int* in_sizes, int n_in,
                              void* d_out, int out_size, void* d_ws, size_t ws_size,
                              hipStream_t stream) {
  (void)n_in; (void)out_size; (void)ws_size;
  const float* latent = (const float*)d_in[0];
  const float* mean   = (const float*)d_in[1];
  const float* logdur = (const float*)d_in[2];
  const int*   textlen = (const int*)d_in[3];
  const int*   mellen  = (const int*)d_in[4];

  int B = in_sizes[3];
  int S = in_sizes[2] / B;
  int C = in_sizes[1] / (B * S);
  int T = in_sizes[0] / (B * C);

  float* out = (float*)d_out;
  float* ll = out + 1;  // reuse attn region [B*T*S] as ll scratch, overwritten later

  char* ws = (char*)d_ws;
  float* lx2    = (float*)ws;            // B*T
  float* lm2    = lx2 + (size_t)B * T;   // B*S
  int*   pathidx = (int*)(lm2 + (size_t)B * S);          // B*T
  float* rowsum  = (float*)(pathidx + (size_t)B * T);    // B*T
  float* nllc    = rowsum + (size_t)B * T;               // B
  float* durc    = nllc + B;                             // B

  k_sums<<<B * T + B * S, 64, 0, stream>>>(latent, mean, lx2, lm2, B * T, B * S, C);

  dim3 g2((T + 63) / 64, (S + 63) / 64, B);
  k_scores<<<g2, 256, 0, stream>>>(latent, mean, lx2, lm2, textlen, mellen, ll, T, S, C);

  k_scan<<<B, 256, 0, stream>>>(ll, textlen, mellen, pathidx, T, S);

  size_t total = (size_t)B * T * S;
  k_scatter<<<(int)((total / 4 + 255) / 256), 256, 0, stream>>>(ll, pathidx, textlen, mellen, B, T, S);

  k_rowloss<<<(B * T) / 4, 256, 0, stream>>>(latent, mean, pathidx, textlen, mellen, rowsum, T, S, C);

  k_batch<<<B, 256, 0, stream>>>(rowsum, pathidx, logdur, textlen, mellen, nllc, durc, T, S, C);

  k_final<<<1, 64, 0, stream>>>(nllc, durc, out, B);
}